// Round 6
// baseline (2396.442 us; speedup 1.0000x reference)
//
#include <hip/hip_runtime.h>
#include <hip/hip_bf16.h>
#include <math.h>

// Problem constants
#define TT 64
#define BB 256      // per-sequence batch
#define BT 512      // total batch (both sequences)
#define DD 300      // embedding dim
#define HH 512      // hidden
#define G4 2048     // 4*H
#define KX 320      // padded x-region K
#define KWP 1024    // WcatP physical K: [hi 512 | lo 512]
#define KC 64       // K chunk per LDS stage (gemm_x)
#define NCHX 5      // KX / KC
#define NBLK 256    // persistent grid size

typedef __attribute__((ext_vector_type(8))) short short8v;
typedef __attribute__((ext_vector_type(4))) float f32x4;
typedef __attribute__((ext_vector_type(4))) unsigned short ushort4v;

__device__ __forceinline__ unsigned short f2bf(float f) {
    union { float f; unsigned int u; } v; v.f = f;
    unsigned int u = v.u;
    u += 0x7fffu + ((u >> 16) & 1u);   // round-to-nearest-even
    return (unsigned short)(u >> 16);
}
__device__ __forceinline__ float bf2f(unsigned short s) {
    union { unsigned int u; float f; } v; v.u = ((unsigned int)s) << 16;
    return v.f;
}
__device__ __forceinline__ float sigm(float x) { return 1.0f / (1.0f + __expf(-x)); }
__device__ __forceinline__ float tanh_f(float x) {
    float ax = fabsf(x);
    if (ax > 15.0f) return (x > 0.0f) ? 1.0f : -1.0f;
    float e = __expf(2.0f * ax);
    float t = 1.0f - 2.0f / (e + 1.0f);
    return (x >= 0.0f) ? t : -t;
}

// ---------------------------------------------------------------------------
// Prep: two weight layouts.
//  WcatP (persistent layout): row g'N = jt*64 + jj*4 + grp,
//    gate g = grp*512 + jt*16 + jj; K = [0,512)=Whh hi bf16, [512,1024)=Whh lo.
//  WihP (gemm_x layout): row g'O = jt*64 + grp*16 + jj.
//  biasP[jt*64 + jj*4 + grp] = b_ih[g] + b_hh[g].
__global__ __launch_bounds__(256) void prep_w(const float* __restrict__ Wih,
                                              const float* __restrict__ Whh,
                                              const float* __restrict__ bih,
                                              const float* __restrict__ bhh,
                                              unsigned short* __restrict__ WcatP,
                                              unsigned short* __restrict__ WihP,
                                              float* __restrict__ biasP)
{
    const int gp = blockIdx.x;            // 0..2047
    const int jt = gp >> 6, r = gp & 63;
    const int grpO = r >> 4, jjO = r & 15;
    const int gO = grpO * 512 + jt * 16 + jjO;
    const int jjN = r >> 2, grpN = r & 3;
    const int gN = grpN * 512 + jt * 16 + jjN;

    for (int k = threadIdx.x; k < KWP; k += 256) {
        unsigned short v;
        if (k < HH) {
            v = f2bf(Whh[(size_t)gN * HH + k]);
        } else {
            float f = Whh[(size_t)gN * HH + (k - HH)];
            unsigned short hi = f2bf(f);
            v = f2bf(f - bf2f(hi));
        }
        WcatP[(size_t)gp * KWP + k] = v;
    }
    for (int k = threadIdx.x; k < KX; k += 256)
        WihP[(size_t)gp * KX + k] = (k < DD) ? f2bf(Wih[(size_t)gO * DD + k])
                                             : (unsigned short)0;
    if (threadIdx.x == 0) biasP[jt * 64 + jjO * 4 + grpO] = bih[gO] + bhh[gO];
}

// Prep: initial h (hi/lo bf16) into ping buffer 0; zero the barrier counters
// (every call -> deterministic across graph replays).
__global__ __launch_bounds__(256) void prep_h(const float* __restrict__ h0a,
                                              const float* __restrict__ h0b,
                                              unsigned short* __restrict__ hhi,
                                              unsigned short* __restrict__ hlo,
                                              unsigned int* __restrict__ bar)
{
    const int b = blockIdx.x; // 0..511
    if (b == 0 && threadIdx.x < TT) bar[threadIdx.x] = 0u;
    for (int j = threadIdx.x; j < HH; j += 256) {
        float hv = (b < BB) ? h0a[b * HH + j] : h0b[(b - BB) * HH + j];
        unsigned short hi = f2bf(hv);
        hhi[b * HH + j] = hi;
        hlo[b * HH + j] = f2bf(hv - bf2f(hi));
    }
}

// Pre-gather embeddings to bf16: Xbf[t*512+b][0..KX) (zero-padded past DD).
__global__ __launch_bounds__(256) void gather_x(const int* __restrict__ s1,
                                                const int* __restrict__ s2,
                                                const float* __restrict__ emb,
                                                unsigned short* __restrict__ Xbf)
{
    const int idx = blockIdx.x * 256 + threadIdx.x;   // TT*BT*40 threads
    const int row = idx / 40;          // t*512 + b
    const int seg = idx - row * 40;    // 8-elem segment within 320
    const int t = row >> 9;
    const int b = row & 511;
    const int tok = (b < BB) ? s1[t * BB + b] : s2[t * BB + (b - BB)];
    const int k = seg * 8;
    short8v v;
    if (k + 8 <= DD) {
        const float* e0 = emb + (size_t)tok * DD + k;
        float4 va = *(const float4*)e0;
        float4 vb = *(const float4*)(e0 + 4);
        v[0] = (short)f2bf(va.x); v[1] = (short)f2bf(va.y);
        v[2] = (short)f2bf(va.z); v[3] = (short)f2bf(va.w);
        v[4] = (short)f2bf(vb.x); v[5] = (short)f2bf(vb.y);
        v[6] = (short)f2bf(vb.z); v[7] = (short)f2bf(vb.w);
    } else {
        #pragma unroll
        for (int e = 0; e < 8; ++e) {
            int c = k + e;
            v[e] = (c < DD) ? (short)f2bf(emb[(size_t)tok * DD + c]) : (short)0;
        }
    }
    *(short8v*)&Xbf[(size_t)row * KX + k] = v;
}

// ---------------------------------------------------------------------------
// xprojP[m][g''] GEMM (unchanged, verified): g'' = jt*64 + jj*4 + grp.
__global__ __launch_bounds__(256) void gemm_x(
    const unsigned short* __restrict__ Xbf,
    const unsigned short* __restrict__ WihP,
    unsigned short* __restrict__ xprojP)
{
    __shared__ __align__(16) unsigned short As[64 * 64];
    __shared__ __align__(16) unsigned short Bs[64 * 64];
    __shared__ __align__(16) float gbuf[64 * 65];

    const int tid = threadIdx.x;
    const int nblk = blockIdx.x & 31;      // g' tile
    const int mblk = blockIdx.x >> 5;      // row tile

    const int lane = tid & 63;
    const int w = tid >> 6;
    const int wr = w >> 1, wc = w & 1;
    const int r16 = lane & 15;
    const int kg8 = lane >> 4;
    const int sl8 = lane >> 3;
    const int gd  = lane & 7;

    f32x4 acc[2][2] = {};

    auto load_chunk = [&](int ch, short8v* va, short8v* vb) {
        const int k0 = ch * KC;
        #pragma unroll
        for (int s = 0; s < 2; ++s) {
            const int r = w * 16 + s * 8 + sl8;
            va[s] = *(const short8v*)(Xbf + (size_t)(mblk * 64 + r) * KX + k0 + gd * 8);
            vb[s] = *(const short8v*)(WihP + (size_t)(nblk * 64 + r) * KX + k0 + gd * 8);
        }
    };
    auto write_chunk = [&](const short8v* va, const short8v* vb) {
        #pragma unroll
        for (int s = 0; s < 2; ++s) {
            const int r = w * 16 + s * 8 + sl8;
            const int g = (gd ^ sl8) << 3;
            *(short8v*)&As[r * 64 + g] = va[s];
            *(short8v*)&Bs[r * 64 + g] = vb[s];
        }
    };
    auto lidx = [&](int r, int ko) { return r * 64 + ((((ko) >> 3) ^ (r & 7)) << 3); };

    short8v va[2], vb[2], na[2], nb[2];
    load_chunk(0, va, vb);
    for (int ch = 0; ch < NCHX; ++ch) {
        write_chunk(va, vb);
        if (ch + 1 < NCHX) load_chunk(ch + 1, na, nb);
        __syncthreads();
        #pragma unroll
        for (int ks = 0; ks < KC; ks += 32) {
            const int ko = ks + kg8 * 8;
            short8v a0 = *(const short8v*)&As[lidx(32 * wr + r16,      ko)];
            short8v a1 = *(const short8v*)&As[lidx(32 * wr + 16 + r16, ko)];
            short8v b0 = *(const short8v*)&Bs[lidx(32 * wc + r16,      ko)];
            short8v b1 = *(const short8v*)&Bs[lidx(32 * wc + 16 + r16, ko)];
            acc[0][0] = __builtin_amdgcn_mfma_f32_16x16x32_bf16(a0, b0, acc[0][0], 0, 0, 0);
            acc[0][1] = __builtin_amdgcn_mfma_f32_16x16x32_bf16(a0, b1, acc[0][1], 0, 0, 0);
            acc[1][0] = __builtin_amdgcn_mfma_f32_16x16x32_bf16(a1, b0, acc[1][0], 0, 0, 0);
            acc[1][1] = __builtin_amdgcn_mfma_f32_16x16x32_bf16(a1, b1, acc[1][1], 0, 0, 0);
        }
        __syncthreads();
        #pragma unroll
        for (int s = 0; s < 2; ++s) { va[s] = na[s]; vb[s] = nb[s]; }
    }

    #pragma unroll
    for (int i = 0; i < 2; ++i)
        #pragma unroll
        for (int j = 0; j < 2; ++j)
            #pragma unroll
            for (int r = 0; r < 4; ++r) {
                int grow = (2 * wr + i) * 16 + kg8 * 4 + r;
                int gcol = (2 * wc + j) * 16 + r16;
                gbuf[grow * 65 + gcol] = acc[i][j][r];
            }
    __syncthreads();

    const int jj = tid & 15;
    const int row0 = tid >> 4;
    #pragma unroll
    for (int u = 0; u < 4; ++u) {
        int row = row0 + 16 * u;
        size_t m = (size_t)(mblk * 64 + row);
        ushort4v o;
        o[0] = f2bf(gbuf[row * 65 +      jj]);
        o[1] = f2bf(gbuf[row * 65 + 16 + jj]);
        o[2] = f2bf(gbuf[row * 65 + 32 + jj]);
        o[3] = f2bf(gbuf[row * 65 + 48 + jj]);
        *(ushort4v*)&xprojP[m * G4 + nblk * 64 + jj * 4] = o;
    }
}

// ---------------------------------------------------------------------------
// Persistent LSTM, normal launch + manual one-shot grid barriers.
// Block (bx=bid&7, jt=bid>>3). W fragments persistent in VGPRs; c in VGPRs;
// A fragments per-lane from global (L2-resident); no LDS in the K loop.
#define MF(a, b, c) __builtin_amdgcn_mfma_f32_16x16x32_bf16(a, b, c, 0, 0, 0)

__global__ __launch_bounds__(256, 1) void lstm_persist(
    const unsigned short* __restrict__ WcatP,
    const float* __restrict__ biasP,
    const unsigned short* __restrict__ xprojP,
    unsigned short* __restrict__ hhi0, unsigned short* __restrict__ hlo0,
    unsigned short* __restrict__ hhi1, unsigned short* __restrict__ hlo1,
    const float* __restrict__ c0a, const float* __restrict__ c0b,
    unsigned int* __restrict__ bar)
{
    __shared__ __align__(16) float gbuf[64 * 68];   // 17408 B

    const int tid = threadIdx.x;
    const int bid = blockIdx.x;
    const int bx = bid & 7;        // batch group
    const int jt = bid >> 3;       // 0..31

    const int lane = tid & 63;
    const int w = tid >> 6;
    const int wr = w >> 1, wc = w & 1;
    const int r16 = lane & 15;
    const int kg8 = lane >> 4;

    // ---- persistent W fragments (one-time load), [group][ks][colblock] ----
    short8v whi[8][2][2], wlo[8][2][2];
    {
        const unsigned short* b0 = WcatP + (size_t)(jt * 64 + 32 * wc + r16) * KWP + kg8 * 8;
        const unsigned short* b1 = b0 + 16 * KWP;
        #pragma unroll
        for (int g = 0; g < 8; ++g)
            #pragma unroll
            for (int ks = 0; ks < 2; ++ks) {
                whi[g][ks][0] = *(const short8v*)(b0 + g * 64 + ks * 32);
                whi[g][ks][1] = *(const short8v*)(b1 + g * 64 + ks * 32);
                wlo[g][ks][0] = *(const short8v*)(b0 + 512 + g * 64 + ks * 32);
                wlo[g][ks][1] = *(const short8v*)(b1 + 512 + g * 64 + ks * 32);
            }
    }

    // ---- persistent epilogue state ----
    const int jj = tid & 15;
    const int row0 = tid >> 4;
    const f32x4 bp = *(const f32x4*)&biasP[jt * 64 + jj * 4];
    float cc[4];
    #pragma unroll
    for (int u = 0; u < 4; ++u) {
        int batch = bx * 64 + row0 + 16 * u;
        cc[u] = (batch < BB) ? c0a[batch * HH + jt * 16 + jj]
                             : c0b[(batch - BB) * HH + jt * 16 + jj];
    }

    const int aoff0 = (bx * 64 + 32 * wr + r16) * HH + kg8 * 8;  // rowblock i=0
    const int aoff1 = aoff0 + 16 * HH;                           // rowblock i=1

    for (int t = 0; t < TT; ++t) {
        const unsigned short* rhi = (t & 1) ? hhi1 : hhi0;
        const unsigned short* rlo = (t & 1) ? hlo1 : hlo0;
        unsigned short* ohi = (t & 1) ? hhi0 : hhi1;
        unsigned short* olo = (t & 1) ? hlo0 : hlo1;

        // xproj prefetch (independent of h) — issue before the barrier
        ushort4v xp[4];
        #pragma unroll
        for (int u = 0; u < 4; ++u) {
            int batch = bx * 64 + row0 + 16 * u;
            xp[u] = *(const ushort4v*)&xprojP[((size_t)t * BT + batch) * G4 + jt * 64 + jj * 4];
        }

        if (t) {
            // ---- manual grid barrier: h of step t-1 globally visible ----
            __syncthreads();                       // block's h stores issued
            if (tid == 0) {
                __threadfence();                   // release h writes (agent)
                __hip_atomic_fetch_add(&bar[t - 1], 1u, __ATOMIC_ACQ_REL,
                                       __HIP_MEMORY_SCOPE_AGENT);
                while (__hip_atomic_load(&bar[t - 1], __ATOMIC_ACQUIRE,
                                         __HIP_MEMORY_SCOPE_AGENT) < NBLK)
                    __builtin_amdgcn_s_sleep(2);
                __threadfence();                   // acquire: invalidate caches
            }
            __syncthreads();
        }

        f32x4 acc[2][2] = {};
        #pragma unroll
        for (int g = 0; g < 8; ++g) {
            short8v ah[2][2], al[2][2];   // [ks][rowblock]
            #pragma unroll
            for (int ks = 0; ks < 2; ++ks) {
                ah[ks][0] = *(const short8v*)(rhi + aoff0 + g * 64 + ks * 32);
                ah[ks][1] = *(const short8v*)(rhi + aoff1 + g * 64 + ks * 32);
                al[ks][0] = *(const short8v*)(rlo + aoff0 + g * 64 + ks * 32);
                al[ks][1] = *(const short8v*)(rlo + aoff1 + g * 64 + ks * 32);
            }
            #pragma unroll
            for (int ks = 0; ks < 2; ++ks)
                #pragma unroll
                for (int i = 0; i < 2; ++i) {
                    acc[i][0] = MF(ah[ks][i], whi[g][ks][0], acc[i][0]);  // hi*Whi
                    acc[i][1] = MF(ah[ks][i], whi[g][ks][1], acc[i][1]);
                }
            #pragma unroll
            for (int ks = 0; ks < 2; ++ks)
                #pragma unroll
                for (int i = 0; i < 2; ++i) {
                    acc[i][0] = MF(al[ks][i], whi[g][ks][0], acc[i][0]);  // lo*Whi
                    acc[i][1] = MF(al[ks][i], whi[g][ks][1], acc[i][1]);
                }
            #pragma unroll
            for (int ks = 0; ks < 2; ++ks)
                #pragma unroll
                for (int i = 0; i < 2; ++i) {
                    acc[i][0] = MF(ah[ks][i], wlo[g][ks][0], acc[i][0]);  // hi*Wlo
                    acc[i][1] = MF(ah[ks][i], wlo[g][ks][1], acc[i][1]);
                }
        }

        // ---- gate exchange through LDS ----
        __syncthreads();
        #pragma unroll
        for (int i = 0; i < 2; ++i)
            #pragma unroll
            for (int j2 = 0; j2 < 2; ++j2)
                #pragma unroll
                for (int r = 0; r < 4; ++r)
                    gbuf[((2 * wr + i) * 16 + kg8 * 4 + r) * 68 + 32 * wc + 16 * j2 + r16]
                        = acc[i][j2][r];
        __syncthreads();

        // ---- cell update: c in VGPR, write h hi/lo ----
        #pragma unroll
        for (int u = 0; u < 4; ++u) {
            int row = row0 + 16 * u;
            int batch = bx * 64 + row;
            f32x4 gv = *(const f32x4*)&gbuf[row * 68 + jj * 4];
            float gi = gv[0] + bp[0] + bf2f(xp[u][0]);
            float gf = gv[1] + bp[1] + bf2f(xp[u][1]);
            float gg = gv[2] + bp[2] + bf2f(xp[u][2]);
            float go = gv[3] + bp[3] + bf2f(xp[u][3]);
            float cn = sigm(gf) * cc[u] + sigm(gi) * tanh_f(gg);
            float hn = sigm(go) * tanh_f(cn);
            cc[u] = cn;
            unsigned short hi = f2bf(hn);
            ohi[batch * HH + jt * 16 + jj] = hi;
            olo[batch * HH + jt * 16 + jj] = f2bf(hn - bf2f(hi));
        }
    }
}

// ---------------------------------------------------------------------------
__global__ __launch_bounds__(64) void finalize(const unsigned short* __restrict__ hhi,
                                               const unsigned short* __restrict__ hlo,
                                               float* __restrict__ out)
{
    const int b = blockIdx.x;       // 0..255
    const int lane = threadIdx.x;   // 64
    float s = 0.0f;
    for (int j = lane; j < HH; j += 64) {
        float ha = bf2f(hhi[b * HH + j]) + bf2f(hlo[b * HH + j]);
        float hb = bf2f(hhi[(b + BB) * HH + j]) + bf2f(hlo[(b + BB) * HH + j]);
        s += fabsf(ha - hb);
    }
    #pragma unroll
    for (int off = 32; off > 0; off >>= 1) s += __shfl_down(s, off);
    if (lane == 0) out[b] = expf(-s);
}

// ---------------------------------------------------------------------------
extern "C" void kernel_launch(void* const* d_in, const int* in_sizes, int n_in,
                              void* d_out, int out_size, void* d_ws, size_t ws_size,
                              hipStream_t stream)
{
    const int*   s1  = (const int*)d_in[0];
    const int*   s2  = (const int*)d_in[1];
    const float* emb = (const float*)d_in[2];
    const float* Wih = (const float*)d_in[3];
    const float* Whh = (const float*)d_in[4];
    const float* bih = (const float*)d_in[5];
    const float* bhh = (const float*)d_in[6];
    const float* h0a = (const float*)d_in[7];
    const float* c0a = (const float*)d_in[8];
    const float* h0b = (const float*)d_in[9];
    const float* c0b = (const float*)d_in[10];
    float* out = (float*)d_out;

    char* ws = (char*)d_ws;
    size_t off = 0;
    unsigned short* WcatP = (unsigned short*)(ws + off); off += (size_t)G4 * KWP * 2;   // 4 MB
    unsigned short* WihP  = (unsigned short*)(ws + off); off += (size_t)G4 * KX * 2;    // 1.3 MB
    float* biasP          = (float*)(ws + off);          off += (size_t)G4 * 4;
    unsigned short* hhi0  = (unsigned short*)(ws + off); off += (size_t)BT * HH * 2;
    unsigned short* hhi1  = (unsigned short*)(ws + off); off += (size_t)BT * HH * 2;
    unsigned short* hlo0  = (unsigned short*)(ws + off); off += (size_t)BT * HH * 2;
    unsigned short* hlo1  = (unsigned short*)(ws + off); off += (size_t)BT * HH * 2;
    unsigned int* bar     = (unsigned int*)(ws + off);   off += 256;                    // 64 used
    unsigned short* Xbf   = (unsigned short*)(ws + off); off += (size_t)TT * BT * KX * 2; // 21 MB
    unsigned short* xprojP= (unsigned short*)(ws + off); off += (size_t)TT * BT * G4 * 2; // 134 MB

    prep_w<<<G4, 256, 0, stream>>>(Wih, Whh, bih, bhh, WcatP, WihP, biasP);
    prep_h<<<BT, 256, 0, stream>>>(h0a, h0b, hhi0, hlo0, bar);
    gather_x<<<(TT * BT * 40) / 256, 256, 0, stream>>>(s1, s2, emb, Xbf);
    gemm_x<<<512 * 32, 256, 0, stream>>>(Xbf, WihP, xprojP);

    lstm_persist<<<NBLK, 256, 0, stream>>>(WcatP, biasP, xprojP,
                                           hhi0, hlo0, hhi1, hlo1,
                                           c0a, c0b, bar);

    // final h written at t=63 into buffer 0
    finalize<<<BB, 64, 0, stream>>>(hhi0, hlo0, out);
}

// Round 7
// 1185.505 us; speedup vs baseline: 2.0215x; 2.0215x over previous
//
#include <hip/hip_runtime.h>
#include <hip/hip_bf16.h>
#include <math.h>

// Problem constants
#define TT 64
#define BB 256      // per-sequence batch
#define BT 512      // total batch (both sequences)
#define DD 300      // embedding dim
#define HH 512      // hidden
#define G4 2048     // 4*H
#define KX 320      // padded x-region K
#define KWP 1024    // WcatP physical K: [hi 512 | lo 512]
#define KC 64       // K chunk per LDS stage (gemm_x)
#define NCHX 5      // KX / KC
#define NBLK 256    // persistent grid size
#define NGRP 32     // blocks per batch-group barrier

typedef __attribute__((ext_vector_type(8))) short short8v;
typedef __attribute__((ext_vector_type(4))) float f32x4;
typedef __attribute__((ext_vector_type(4))) unsigned short ushort4v;

__device__ __forceinline__ unsigned short f2bf(float f) {
    union { float f; unsigned int u; } v; v.f = f;
    unsigned int u = v.u;
    u += 0x7fffu + ((u >> 16) & 1u);   // round-to-nearest-even
    return (unsigned short)(u >> 16);
}
__device__ __forceinline__ float bf2f(unsigned short s) {
    union { unsigned int u; float f; } v; v.u = ((unsigned int)s) << 16;
    return v.f;
}
__device__ __forceinline__ float sigm(float x) { return 1.0f / (1.0f + __expf(-x)); }
__device__ __forceinline__ float tanh_f(float x) {
    float ax = fabsf(x);
    if (ax > 15.0f) return (x > 0.0f) ? 1.0f : -1.0f;
    float e = __expf(2.0f * ax);
    float t = 1.0f - 2.0f / (e + 1.0f);
    return (x >= 0.0f) ? t : -t;
}

// Coherent (LLC-level, cache-bypassing) h exchange: relaxed agent-scope atomics.
__device__ __forceinline__ short8v load_h8(const unsigned short* p) {
    union { unsigned long long q[2]; short8v v; } u;
    const unsigned long long* q = (const unsigned long long*)p;
    u.q[0] = __hip_atomic_load(q,     __ATOMIC_RELAXED, __HIP_MEMORY_SCOPE_AGENT);
    u.q[1] = __hip_atomic_load(q + 1, __ATOMIC_RELAXED, __HIP_MEMORY_SCOPE_AGENT);
    return u.v;
}
__device__ __forceinline__ void store_h(unsigned short* p, unsigned short v) {
    __hip_atomic_store(p, v, __ATOMIC_RELAXED, __HIP_MEMORY_SCOPE_AGENT);
}

// ---------------------------------------------------------------------------
// Prep: two weight layouts (unchanged from R6, verified).
__global__ __launch_bounds__(256) void prep_w(const float* __restrict__ Wih,
                                              const float* __restrict__ Whh,
                                              const float* __restrict__ bih,
                                              const float* __restrict__ bhh,
                                              unsigned short* __restrict__ WcatP,
                                              unsigned short* __restrict__ WihP,
                                              float* __restrict__ biasP)
{
    const int gp = blockIdx.x;            // 0..2047
    const int jt = gp >> 6, r = gp & 63;
    const int grpO = r >> 4, jjO = r & 15;
    const int gO = grpO * 512 + jt * 16 + jjO;
    const int jjN = r >> 2, grpN = r & 3;
    const int gN = grpN * 512 + jt * 16 + jjN;

    for (int k = threadIdx.x; k < KWP; k += 256) {
        unsigned short v;
        if (k < HH) {
            v = f2bf(Whh[(size_t)gN * HH + k]);
        } else {
            float f = Whh[(size_t)gN * HH + (k - HH)];
            unsigned short hi = f2bf(f);
            v = f2bf(f - bf2f(hi));
        }
        WcatP[(size_t)gp * KWP + k] = v;
    }
    for (int k = threadIdx.x; k < KX; k += 256)
        WihP[(size_t)gp * KX + k] = (k < DD) ? f2bf(Wih[(size_t)gO * DD + k])
                                             : (unsigned short)0;
    if (threadIdx.x == 0) biasP[jt * 64 + jjO * 4 + grpO] = bih[gO] + bhh[gO];
}

// Prep: initial h into ping buffer 0; zero the 512 group-barrier counters.
__global__ __launch_bounds__(256) void prep_h(const float* __restrict__ h0a,
                                              const float* __restrict__ h0b,
                                              unsigned short* __restrict__ hhi,
                                              unsigned short* __restrict__ hlo,
                                              unsigned int* __restrict__ bar)
{
    const int b = blockIdx.x; // 0..511
    if (b == 0)
        for (int i = threadIdx.x; i < TT * 8; i += 256) bar[i] = 0u;
    for (int j = threadIdx.x; j < HH; j += 256) {
        float hv = (b < BB) ? h0a[b * HH + j] : h0b[(b - BB) * HH + j];
        unsigned short hi = f2bf(hv);
        hhi[b * HH + j] = hi;
        hlo[b * HH + j] = f2bf(hv - bf2f(hi));
    }
}

// Pre-gather embeddings to bf16 (unchanged).
__global__ __launch_bounds__(256) void gather_x(const int* __restrict__ s1,
                                                const int* __restrict__ s2,
                                                const float* __restrict__ emb,
                                                unsigned short* __restrict__ Xbf)
{
    const int idx = blockIdx.x * 256 + threadIdx.x;   // TT*BT*40 threads
    const int row = idx / 40;
    const int seg = idx - row * 40;
    const int t = row >> 9;
    const int b = row & 511;
    const int tok = (b < BB) ? s1[t * BB + b] : s2[t * BB + (b - BB)];
    const int k = seg * 8;
    short8v v;
    if (k + 8 <= DD) {
        const float* e0 = emb + (size_t)tok * DD + k;
        float4 va = *(const float4*)e0;
        float4 vb = *(const float4*)(e0 + 4);
        v[0] = (short)f2bf(va.x); v[1] = (short)f2bf(va.y);
        v[2] = (short)f2bf(va.z); v[3] = (short)f2bf(va.w);
        v[4] = (short)f2bf(vb.x); v[5] = (short)f2bf(vb.y);
        v[6] = (short)f2bf(vb.z); v[7] = (short)f2bf(vb.w);
    } else {
        #pragma unroll
        for (int e = 0; e < 8; ++e) {
            int c = k + e;
            v[e] = (c < DD) ? (short)f2bf(emb[(size_t)tok * DD + c]) : (short)0;
        }
    }
    *(short8v*)&Xbf[(size_t)row * KX + k] = v;
}

// ---------------------------------------------------------------------------
// xprojP[m][g''] GEMM (unchanged, verified): g'' = jt*64 + jj*4 + grp.
__global__ __launch_bounds__(256) void gemm_x(
    const unsigned short* __restrict__ Xbf,
    const unsigned short* __restrict__ WihP,
    unsigned short* __restrict__ xprojP)
{
    __shared__ __align__(16) unsigned short As[64 * 64];
    __shared__ __align__(16) unsigned short Bs[64 * 64];
    __shared__ __align__(16) float gbuf[64 * 65];

    const int tid = threadIdx.x;
    const int nblk = blockIdx.x & 31;      // g' tile
    const int mblk = blockIdx.x >> 5;      // row tile

    const int lane = tid & 63;
    const int w = tid >> 6;
    const int wr = w >> 1, wc = w & 1;
    const int r16 = lane & 15;
    const int kg8 = lane >> 4;
    const int sl8 = lane >> 3;
    const int gd  = lane & 7;

    f32x4 acc[2][2] = {};

    auto load_chunk = [&](int ch, short8v* va, short8v* vb) {
        const int k0 = ch * KC;
        #pragma unroll
        for (int s = 0; s < 2; ++s) {
            const int r = w * 16 + s * 8 + sl8;
            va[s] = *(const short8v*)(Xbf + (size_t)(mblk * 64 + r) * KX + k0 + gd * 8);
            vb[s] = *(const short8v*)(WihP + (size_t)(nblk * 64 + r) * KX + k0 + gd * 8);
        }
    };
    auto write_chunk = [&](const short8v* va, const short8v* vb) {
        #pragma unroll
        for (int s = 0; s < 2; ++s) {
            const int r = w * 16 + s * 8 + sl8;
            const int g = (gd ^ sl8) << 3;
            *(short8v*)&As[r * 64 + g] = va[s];
            *(short8v*)&Bs[r * 64 + g] = vb[s];
        }
    };
    auto lidx = [&](int r, int ko) { return r * 64 + ((((ko) >> 3) ^ (r & 7)) << 3); };

    short8v va[2], vb[2], na[2], nb[2];
    load_chunk(0, va, vb);
    for (int ch = 0; ch < NCHX; ++ch) {
        write_chunk(va, vb);
        if (ch + 1 < NCHX) load_chunk(ch + 1, na, nb);
        __syncthreads();
        #pragma unroll
        for (int ks = 0; ks < KC; ks += 32) {
            const int ko = ks + kg8 * 8;
            short8v a0 = *(const short8v*)&As[lidx(32 * wr + r16,      ko)];
            short8v a1 = *(const short8v*)&As[lidx(32 * wr + 16 + r16, ko)];
            short8v b0 = *(const short8v*)&Bs[lidx(32 * wc + r16,      ko)];
            short8v b1 = *(const short8v*)&Bs[lidx(32 * wc + 16 + r16, ko)];
            acc[0][0] = __builtin_amdgcn_mfma_f32_16x16x32_bf16(a0, b0, acc[0][0], 0, 0, 0);
            acc[0][1] = __builtin_amdgcn_mfma_f32_16x16x32_bf16(a0, b1, acc[0][1], 0, 0, 0);
            acc[1][0] = __builtin_amdgcn_mfma_f32_16x16x32_bf16(a1, b0, acc[1][0], 0, 0, 0);
            acc[1][1] = __builtin_amdgcn_mfma_f32_16x16x32_bf16(a1, b1, acc[1][1], 0, 0, 0);
        }
        __syncthreads();
        #pragma unroll
        for (int s = 0; s < 2; ++s) { va[s] = na[s]; vb[s] = nb[s]; }
    }

    #pragma unroll
    for (int i = 0; i < 2; ++i)
        #pragma unroll
        for (int j = 0; j < 2; ++j)
            #pragma unroll
            for (int r = 0; r < 4; ++r) {
                int grow = (2 * wr + i) * 16 + kg8 * 4 + r;
                int gcol = (2 * wc + j) * 16 + r16;
                gbuf[grow * 65 + gcol] = acc[i][j][r];
            }
    __syncthreads();

    const int jj = tid & 15;
    const int row0 = tid >> 4;
    #pragma unroll
    for (int u = 0; u < 4; ++u) {
        int row = row0 + 16 * u;
        size_t m = (size_t)(mblk * 64 + row);
        ushort4v o;
        o[0] = f2bf(gbuf[row * 65 +      jj]);
        o[1] = f2bf(gbuf[row * 65 + 16 + jj]);
        o[2] = f2bf(gbuf[row * 65 + 32 + jj]);
        o[3] = f2bf(gbuf[row * 65 + 48 + jj]);
        *(ushort4v*)&xprojP[m * G4 + nblk * 64 + jj * 4] = o;
    }
}

// ---------------------------------------------------------------------------
// Persistent LSTM. Per-GROUP (32-block) barriers; h exchanged via relaxed
// agent-scope atomics (LLC-coherent, no L2 flush fences). W/c in VGPRs.
#define MF(a, b, c) __builtin_amdgcn_mfma_f32_16x16x32_bf16(a, b, c, 0, 0, 0)

__global__ __launch_bounds__(256, 1) void lstm_persist(
    const unsigned short* __restrict__ WcatP,
    const float* __restrict__ biasP,
    const unsigned short* __restrict__ xprojP,
    unsigned short* __restrict__ hhi0, unsigned short* __restrict__ hlo0,
    unsigned short* __restrict__ hhi1, unsigned short* __restrict__ hlo1,
    const float* __restrict__ c0a, const float* __restrict__ c0b,
    unsigned int* __restrict__ bar)
{
    __shared__ __align__(16) float gbuf[64 * 68];   // 17408 B

    const int tid = threadIdx.x;
    const int bid = blockIdx.x;
    const int bx = bid & 7;        // batch group (recurrence-independent groups)
    const int jt = bid >> 3;       // 0..31

    const int lane = tid & 63;
    const int w = tid >> 6;
    const int wr = w >> 1, wc = w & 1;
    const int r16 = lane & 15;
    const int kg8 = lane >> 4;

    // ---- persistent W fragments (one-time load), [group][ks][colblock] ----
    short8v whi[8][2][2], wlo[8][2][2];
    {
        const unsigned short* b0 = WcatP + (size_t)(jt * 64 + 32 * wc + r16) * KWP + kg8 * 8;
        const unsigned short* b1 = b0 + 16 * KWP;
        #pragma unroll
        for (int g = 0; g < 8; ++g)
            #pragma unroll
            for (int ks = 0; ks < 2; ++ks) {
                whi[g][ks][0] = *(const short8v*)(b0 + g * 64 + ks * 32);
                whi[g][ks][1] = *(const short8v*)(b1 + g * 64 + ks * 32);
                wlo[g][ks][0] = *(const short8v*)(b0 + 512 + g * 64 + ks * 32);
                wlo[g][ks][1] = *(const short8v*)(b1 + 512 + g * 64 + ks * 32);
            }
    }

    // ---- persistent epilogue state ----
    const int jj = tid & 15;
    const int row0 = tid >> 4;
    const f32x4 bp = *(const f32x4*)&biasP[jt * 64 + jj * 4];
    float cc[4];
    #pragma unroll
    for (int u = 0; u < 4; ++u) {
        int batch = bx * 64 + row0 + 16 * u;
        cc[u] = (batch < BB) ? c0a[batch * HH + jt * 16 + jj]
                             : c0b[(batch - BB) * HH + jt * 16 + jj];
    }

    const int aoff0 = (bx * 64 + 32 * wr + r16) * HH + kg8 * 8;  // rowblock i=0
    const int aoff1 = aoff0 + 16 * HH;                           // rowblock i=1

    for (int t = 0; t < TT; ++t) {
        const unsigned short* rhi = (t & 1) ? hhi1 : hhi0;
        const unsigned short* rlo = (t & 1) ? hlo1 : hlo0;
        unsigned short* ohi = (t & 1) ? hhi0 : hhi1;
        unsigned short* olo = (t & 1) ? hlo0 : hlo1;

        // xproj prefetch (independent of h) — issue before the barrier wait
        ushort4v xp[4];
        #pragma unroll
        for (int u = 0; u < 4; ++u) {
            int batch = bx * 64 + row0 + 16 * u;
            xp[u] = *(const ushort4v*)&xprojP[((size_t)t * BT + batch) * G4 + jt * 64 + jj * 4];
        }

        if (t) {
            // ---- group barrier WAIT: h(t-1) of this batch group ready ----
            if (tid == 0) {
                while (__hip_atomic_load(&bar[(t - 1) * 8 + bx], __ATOMIC_RELAXED,
                                         __HIP_MEMORY_SCOPE_AGENT) < NGRP)
                    __builtin_amdgcn_s_sleep(1);
            }
            __syncthreads();
            asm volatile("" ::: "memory");   // no compile-time hoist of h loads
        }

        f32x4 acc[2][2] = {};
        #pragma unroll
        for (int g = 0; g < 8; ++g) {
            short8v ah[2][2], al[2][2];   // [ks][rowblock]
            #pragma unroll
            for (int ks = 0; ks < 2; ++ks) {
                ah[ks][0] = load_h8(rhi + aoff0 + g * 64 + ks * 32);
                ah[ks][1] = load_h8(rhi + aoff1 + g * 64 + ks * 32);
                al[ks][0] = load_h8(rlo + aoff0 + g * 64 + ks * 32);
                al[ks][1] = load_h8(rlo + aoff1 + g * 64 + ks * 32);
            }
            #pragma unroll
            for (int ks = 0; ks < 2; ++ks)
                #pragma unroll
                for (int i = 0; i < 2; ++i) {
                    acc[i][0] = MF(ah[ks][i], whi[g][ks][0], acc[i][0]);  // hi*Whi
                    acc[i][1] = MF(ah[ks][i], whi[g][ks][1], acc[i][1]);
                }
            #pragma unroll
            for (int ks = 0; ks < 2; ++ks)
                #pragma unroll
                for (int i = 0; i < 2; ++i) {
                    acc[i][0] = MF(al[ks][i], whi[g][ks][0], acc[i][0]);  // lo*Whi
                    acc[i][1] = MF(al[ks][i], whi[g][ks][1], acc[i][1]);
                }
            #pragma unroll
            for (int ks = 0; ks < 2; ++ks)
                #pragma unroll
                for (int i = 0; i < 2; ++i) {
                    acc[i][0] = MF(ah[ks][i], wlo[g][ks][0], acc[i][0]);  // hi*Wlo
                    acc[i][1] = MF(ah[ks][i], wlo[g][ks][1], acc[i][1]);
                }
        }

        // ---- gate exchange through LDS ----
        __syncthreads();
        #pragma unroll
        for (int i = 0; i < 2; ++i)
            #pragma unroll
            for (int j2 = 0; j2 < 2; ++j2)
                #pragma unroll
                for (int r = 0; r < 4; ++r)
                    gbuf[((2 * wr + i) * 16 + kg8 * 4 + r) * 68 + 32 * wc + 16 * j2 + r16]
                        = acc[i][j2][r];
        __syncthreads();

        // ---- cell update: c in VGPR, write h hi/lo via coherent stores ----
        #pragma unroll
        for (int u = 0; u < 4; ++u) {
            int row = row0 + 16 * u;
            int batch = bx * 64 + row;
            f32x4 gv = *(const f32x4*)&gbuf[row * 68 + jj * 4];
            float gi = gv[0] + bp[0] + bf2f(xp[u][0]);
            float gf = gv[1] + bp[1] + bf2f(xp[u][1]);
            float gg = gv[2] + bp[2] + bf2f(xp[u][2]);
            float go = gv[3] + bp[3] + bf2f(xp[u][3]);
            float cn = sigm(gf) * cc[u] + sigm(gi) * tanh_f(gg);
            float hn = sigm(go) * tanh_f(cn);
            cc[u] = cn;
            unsigned short hi = f2bf(hn);
            store_h(&ohi[batch * HH + jt * 16 + jj], hi);
            store_h(&olo[batch * HH + jt * 16 + jj], f2bf(hn - bf2f(hi)));
        }

        if (t + 1 < TT) {
            // ---- group barrier ARRIVE: h(t) stores are LLC-visible ----
            asm volatile("s_waitcnt vmcnt(0)" ::: "memory");  // per-wave drain
            __syncthreads();
            if (tid == 0)
                __hip_atomic_fetch_add(&bar[t * 8 + bx], 1u, __ATOMIC_RELAXED,
                                       __HIP_MEMORY_SCOPE_AGENT);
        }
    }
}

// ---------------------------------------------------------------------------
__global__ __launch_bounds__(64) void finalize(const unsigned short* __restrict__ hhi,
                                               const unsigned short* __restrict__ hlo,
                                               float* __restrict__ out)
{
    const int b = blockIdx.x;       // 0..255
    const int lane = threadIdx.x;   // 64
    float s = 0.0f;
    for (int j = lane; j < HH; j += 64) {
        float ha = bf2f(hhi[b * HH + j]) + bf2f(hlo[b * HH + j]);
        float hb = bf2f(hhi[(b + BB) * HH + j]) + bf2f(hlo[(b + BB) * HH + j]);
        s += fabsf(ha - hb);
    }
    #pragma unroll
    for (int off = 32; off > 0; off >>= 1) s += __shfl_down(s, off);
    if (lane == 0) out[b] = expf(-s);
}

// ---------------------------------------------------------------------------
extern "C" void kernel_launch(void* const* d_in, const int* in_sizes, int n_in,
                              void* d_out, int out_size, void* d_ws, size_t ws_size,
                              hipStream_t stream)
{
    const int*   s1  = (const int*)d_in[0];
    const int*   s2  = (const int*)d_in[1];
    const float* emb = (const float*)d_in[2];
    const float* Wih = (const float*)d_in[3];
    const float* Whh = (const float*)d_in[4];
    const float* bih = (const float*)d_in[5];
    const float* bhh = (const float*)d_in[6];
    const float* h0a = (const float*)d_in[7];
    const float* c0a = (const float*)d_in[8];
    const float* h0b = (const float*)d_in[9];
    const float* c0b = (const float*)d_in[10];
    float* out = (float*)d_out;

    char* ws = (char*)d_ws;
    size_t off = 0;
    unsigned short* WcatP = (unsigned short*)(ws + off); off += (size_t)G4 * KWP * 2;   // 4 MB
    unsigned short* WihP  = (unsigned short*)(ws + off); off += (size_t)G4 * KX * 2;    // 1.3 MB
    float* biasP          = (float*)(ws + off);          off += (size_t)G4 * 4;
    unsigned short* hhi0  = (unsigned short*)(ws + off); off += (size_t)BT * HH * 2;
    unsigned short* hhi1  = (unsigned short*)(ws + off); off += (size_t)BT * HH * 2;
    unsigned short* hlo0  = (unsigned short*)(ws + off); off += (size_t)BT * HH * 2;
    unsigned short* hlo1  = (unsigned short*)(ws + off); off += (size_t)BT * HH * 2;
    unsigned int* bar     = (unsigned int*)(ws + off);   off += (size_t)TT * 8 * 4;     // 2 KB
    unsigned short* Xbf   = (unsigned short*)(ws + off); off += (size_t)TT * BT * KX * 2; // 21 MB
    unsigned short* xprojP= (unsigned short*)(ws + off); off += (size_t)TT * BT * G4 * 2; // 134 MB

    prep_w<<<G4, 256, 0, stream>>>(Wih, Whh, bih, bhh, WcatP, WihP, biasP);
    prep_h<<<BT, 256, 0, stream>>>(h0a, h0b, hhi0, hlo0, bar);
    gather_x<<<(TT * BT * 40) / 256, 256, 0, stream>>>(s1, s2, emb, Xbf);
    gemm_x<<<512 * 32, 256, 0, stream>>>(Xbf, WihP, xprojP);

    lstm_persist<<<NBLK, 256, 0, stream>>>(WcatP, biasP, xprojP,
                                           hhi0, hlo0, hhi1, hlo1,
                                           c0a, c0b, bar);

    // final h written at t=63 into buffer 0
    finalize<<<BB, 64, 0, stream>>>(hhi0, hlo0, out);
}